// Round 1
// baseline (1432.160 us; speedup 1.0000x reference)
//
#include <hip/hip_runtime.h>
#include <hip/hip_bf16.h>

// ---------------------------------------------------------------------------
// SeqdistModel (bonito CTC-CRF): conv(stride5)+tanh -> linear -> 5*tanh scores
// -> log-semiring forward (logZ) -> out = scores - logZ/T
// Shapes: x[32,1,4000], conv_w[320,1,19], conv_b[320], lin_w[320,5120],
//         lin_b[5120]; out [800,32,5120] fp32.
// ---------------------------------------------------------------------------

typedef __attribute__((ext_vector_type(8))) short bf16x8;
typedef __attribute__((ext_vector_type(4))) float f32x4;

#define T_STEPS 800
#define NBATCH 32
#define FEAT 320
#define CNZ 5120
#define MROWS (T_STEPS * NBATCH)   // 25600

__device__ __forceinline__ float fast_tanh(float x) {
    // tanh(x) = 1 - 2/(e^{2x}+1);  e^{2x} = 2^{x * 2*log2(e)}
    float e = exp2f(x * 2.8853900817779268f);
    return 1.0f - 2.0f * __builtin_amdgcn_rcpf(e + 1.0f);
}

// ---- 1. conv (stride 5, SAME: pad 7/7) + tanh -> bf16 y[25600,320] ---------
__global__ __launch_bounds__(320) void conv_kernel(
    const float* __restrict__ x, const float* __restrict__ w,
    const float* __restrict__ b, __hip_bfloat16* __restrict__ y) {
    int m = blockIdx.x;            // m = t*32 + n
    int t = m >> 5, n = m & 31;
    int f = threadIdx.x;
    __shared__ float xs[19];
    int base = t * 5 - 7;
    if (f < 19) {
        int pos = base + f;
        xs[f] = (pos >= 0 && pos < 4000) ? x[n * 4000 + pos] : 0.0f;
    }
    __syncthreads();
    float acc = b[f];
#pragma unroll
    for (int k = 0; k < 19; ++k) acc = fmaf(xs[k], w[f * 19 + k], acc);
    y[(size_t)m * FEAT + f] = __float2bfloat16(fast_tanh(acc));
}

// ---- 2. transpose lin_w [320,5120] fp32 -> Wt [5120,320] bf16 --------------
__global__ __launch_bounds__(256) void transpose_w(
    const float* __restrict__ W, __hip_bfloat16* __restrict__ Wt) {
    __shared__ float tile[64][65];
    int nb = blockIdx.x * 64, kb = blockIdx.y * 64;
    int tx = threadIdx.x & 63, ty = threadIdx.x >> 6;   // 64 x 4
#pragma unroll
    for (int r = 0; r < 64; r += 4)
        tile[ty + r][tx] = W[(size_t)(kb + ty + r) * CNZ + nb + tx];
    __syncthreads();
#pragma unroll
    for (int r = 0; r < 64; r += 4) {
        int nn = ty + r;
        Wt[(size_t)(nb + nn) * FEAT + kb + tx] = __float2bfloat16(tile[tx][nn]);
    }
}

// ---- 3. GEMM: scores[m,n] = 5*tanh(sum_k A[m,k]*Wt[n,k] + bias[n]) ---------
#define GBM 128
#define GBN 128
#define GBK 64
#define LDK 72   // 64 + 8 shorts pad (keeps 16B alignment, breaks bank stride)

__global__ __launch_bounds__(256) void gemm_kernel(
    const __hip_bfloat16* __restrict__ A,    // [25600,320] bf16
    const __hip_bfloat16* __restrict__ Bt,   // [5120,320]  bf16
    const float* __restrict__ bias,          // [5120]
    float* __restrict__ out) {               // [25600,5120] fp32
    __shared__ __align__(16) short As[GBM * LDK];
    __shared__ __align__(16) short Bs[GBN * LDK];
    const int K = FEAT;
    int bm0 = blockIdx.x * GBM;
    int bn0 = blockIdx.y * GBN;
    int tid = threadIdx.x;
    int wave = tid >> 6, lane = tid & 63;
    int wm = (wave >> 1) * 64, wn = (wave & 1) * 64;
    int col = lane & 15, quad = lane >> 4;

    f32x4 acc[4][4];
#pragma unroll
    for (int i = 0; i < 4; ++i)
#pragma unroll
        for (int j = 0; j < 4; ++j) acc[i][j] = (f32x4){0.f, 0.f, 0.f, 0.f};

    for (int k0 = 0; k0 < K; k0 += GBK) {
#pragma unroll
        for (int p = 0; p < 4; ++p) {
            int i = p * 256 + tid;
            int row = i >> 3, cg = i & 7;
            *(int4*)&As[row * LDK + cg * 8] =
                *(const int4*)&A[(size_t)(bm0 + row) * K + k0 + cg * 8];
            *(int4*)&Bs[row * LDK + cg * 8] =
                *(const int4*)&Bt[(size_t)(bn0 + row) * K + k0 + cg * 8];
        }
        __syncthreads();
#pragma unroll
        for (int kk = 0; kk < GBK; kk += 32) {
            bf16x8 af[4], bfr[4];
#pragma unroll
            for (int i = 0; i < 4; ++i)
                af[i] = *(bf16x8*)&As[(wm + i * 16 + col) * LDK + kk + quad * 8];
#pragma unroll
            for (int j = 0; j < 4; ++j)
                bfr[j] = *(bf16x8*)&Bs[(wn + j * 16 + col) * LDK + kk + quad * 8];
#pragma unroll
            for (int i = 0; i < 4; ++i)
#pragma unroll
                for (int j = 0; j < 4; ++j)
                    acc[i][j] = __builtin_amdgcn_mfma_f32_16x16x32_bf16(
                        af[i], bfr[j], acc[i][j], 0, 0, 0);
        }
        __syncthreads();
    }
    // epilogue: D row = quad*4+r (M), col = lane&15 (N)
#pragma unroll
    for (int j = 0; j < 4; ++j) {
        int n_g = bn0 + wn + j * 16 + col;
        float bj = bias[n_g];
#pragma unroll
        for (int i = 0; i < 4; ++i) {
            int m_base = bm0 + wm + i * 16 + quad * 4;
#pragma unroll
            for (int r = 0; r < 4; ++r) {
                out[(size_t)(m_base + r) * CNZ + n_g] =
                    5.0f * fast_tanh(acc[i][j][r] + bj);
            }
        }
    }
}

// ---- 4. forward algorithm (log-semiring), one block per batch element ------
// idx[c] = {c, c>>2, (c>>2)+256, (c>>2)+512, (c>>2)+768}
// Key structure: states {4u,4u+1,4u+2,4u+3} share predecessor set
// {u, u+256, u+512, u+768}; their 20 scores are contiguous & 16B-aligned.
// -> 256 threads, 4 states/thread: 5x dwordx4 score loads, 1x ds_read_b128 +
//    4x ds_read_b32 alpha reads, 1x ds_write_b128, 4-wave barrier.
// Alpha kept in log2 domain (a2 = alpha*log2e) so the L2E scaling folds into
// one FMA per transition. Depth-4 register prefetch pipeline covers HBM lat.

__device__ __forceinline__ float lse5_2(float s0, float s1, float s2, float s3,
                                        float s4, float a0, float a1, float a2,
                                        float a3, float a4) {
    const float L2E = 1.4426950408889634f;
    float x0 = fmaf(s0, L2E, a0);
    float x1 = fmaf(s1, L2E, a1);
    float x2 = fmaf(s2, L2E, a2);
    float x3 = fmaf(s3, L2E, a3);
    float x4 = fmaf(s4, L2E, a4);
    float mx = fmaxf(fmaxf(fmaxf(x0, x1), fmaxf(x2, x3)), x4);
    float sum = __builtin_amdgcn_exp2f(x0 - mx) + __builtin_amdgcn_exp2f(x1 - mx) +
                __builtin_amdgcn_exp2f(x2 - mx) + __builtin_amdgcn_exp2f(x3 - mx) +
                __builtin_amdgcn_exp2f(x4 - mx);
    return __builtin_amdgcn_logf(sum) + mx;   // log2(sum) + mx
}

#define LOADP(P, TT) do {                                                      \
    int tc_ = (TT) < T_STEPS ? (TT) : (T_STEPS - 1);                           \
    const float4* p4_ = (const float4*)(base + (size_t)tc_ * tstride);         \
    P[0] = p4_[0]; P[1] = p4_[1]; P[2] = p4_[2]; P[3] = p4_[3]; P[4] = p4_[4]; \
} while (0)

#define FSTEP(P, TT, cur, nxt) do {                                            \
    float s0_ = P[0].x, s1_ = P[0].y, s2_ = P[0].z, s3_ = P[0].w, s4_ = P[1].x;\
    float t0_ = P[1].y, t1_ = P[1].z, t2_ = P[1].w, t3_ = P[2].x, t4_ = P[2].y;\
    float u0_ = P[2].z, u1_ = P[2].w, u2_ = P[3].x, u3_ = P[3].y, u4_ = P[3].z;\
    float v0_ = P[3].w, v1_ = P[4].x, v2_ = P[4].y, v3_ = P[4].z, v4_ = P[4].w;\
    LOADP(P, TT);                                                              \
    float aq0_ = (cur)[tid], aq1_ = (cur)[tid + 256];                          \
    float aq2_ = (cur)[tid + 512], aq3_ = (cur)[tid + 768];                    \
    float4 ao_ = *(const float4*)&(cur)[4 * tid];                              \
    float4 r_;                                                                 \
    r_.x = lse5_2(s0_, s1_, s2_, s3_, s4_, ao_.x, aq0_, aq1_, aq2_, aq3_);     \
    r_.y = lse5_2(t0_, t1_, t2_, t3_, t4_, ao_.y, aq0_, aq1_, aq2_, aq3_);     \
    r_.z = lse5_2(u0_, u1_, u2_, u3_, u4_, ao_.z, aq0_, aq1_, aq2_, aq3_);     \
    r_.w = lse5_2(v0_, v1_, v2_, v3_, v4_, ao_.w, aq0_, aq1_, aq2_, aq3_);     \
    *(float4*)&(nxt)[4 * tid] = r_;                                            \
    __syncthreads();                                                           \
} while (0)

__global__ __launch_bounds__(256) void forward_kernel(
    const float* __restrict__ scores, float* __restrict__ corr) {
    __shared__ float A0[1024];
    __shared__ float A1[1024];
    const int tid = threadIdx.x;
    const int n = blockIdx.x;
    const float LN2 = 0.6931471805599453f;

    *(float4*)&A0[4 * tid] = (float4){0.f, 0.f, 0.f, 0.f};
    __syncthreads();

    const size_t tstride = (size_t)NBATCH * CNZ;
    const float* base = scores + (size_t)n * CNZ + tid * 20;

    float4 P0[5], P1[5], P2[5], P3[5];
    LOADP(P0, 0); LOADP(P1, 1); LOADP(P2, 2); LOADP(P3, 3);

    for (int t = 0; t < T_STEPS; t += 4) {
        FSTEP(P0, t + 4, A0, A1);
        FSTEP(P1, t + 5, A1, A0);
        FSTEP(P2, t + 6, A0, A1);
        FSTEP(P3, t + 7, A1, A0);
    }
    // final alpha (log2 domain) is in A0 (last step writes A0)
    float4 v = *(const float4*)&A0[4 * tid];
    float pm = fmaxf(fmaxf(v.x, v.y), fmaxf(v.z, v.w));
    A1[tid] = pm;
    __syncthreads();
#pragma unroll
    for (int s = 128; s > 0; s >>= 1) {
        if (tid < s) A1[tid] = fmaxf(A1[tid], A1[tid + s]);
        __syncthreads();
    }
    float mx = A1[0];
    __syncthreads();
    float ps = __builtin_amdgcn_exp2f(v.x - mx) + __builtin_amdgcn_exp2f(v.y - mx) +
               __builtin_amdgcn_exp2f(v.z - mx) + __builtin_amdgcn_exp2f(v.w - mx);
    A1[tid] = ps;
    __syncthreads();
#pragma unroll
    for (int s = 128; s > 0; s >>= 1) {
        if (tid < s) A1[tid] += A1[tid + s];
        __syncthreads();
    }
    if (tid == 0)
        corr[n] = (__builtin_amdgcn_logf(A1[0]) + mx) * LN2 * (1.0f / (float)T_STEPS);
}

// ---- 5. out -= corr[n]  (float4, n = (i4/1280) & 31) -----------------------
__global__ __launch_bounds__(256) void sub_kernel(
    float* __restrict__ out, const float* __restrict__ corr) {
    size_t i4 = (size_t)blockIdx.x * blockDim.x + threadIdx.x;
    float cc = corr[(i4 / (CNZ / 4)) & (NBATCH - 1)];
    float4* o4 = (float4*)out;
    float4 v = o4[i4];
    v.x -= cc; v.y -= cc; v.z -= cc; v.w -= cc;
    o4[i4] = v;
}

extern "C" void kernel_launch(void* const* d_in, const int* in_sizes, int n_in,
                              void* d_out, int out_size, void* d_ws, size_t ws_size,
                              hipStream_t stream) {
    const float* x      = (const float*)d_in[0];
    const float* conv_w = (const float*)d_in[1];
    const float* conv_b = (const float*)d_in[2];
    const float* lin_w  = (const float*)d_in[3];
    const float* lin_b  = (const float*)d_in[4];
    float* out = (float*)d_out;

    char* ws = (char*)d_ws;
    __hip_bfloat16* y  = (__hip_bfloat16*)ws;                       // 16,384,000 B
    __hip_bfloat16* wt = (__hip_bfloat16*)(ws + 16384000);          //  3,276,800 B
    float* corr        = (float*)(ws + 16384000 + 3276800);         //        128 B

    conv_kernel<<<MROWS, 320, 0, stream>>>(x, conv_w, conv_b, y);
    transpose_w<<<dim3(CNZ / 64, FEAT / 64), 256, 0, stream>>>(lin_w, wt);
    gemm_kernel<<<dim3(MROWS / GBM, CNZ / GBN), 256, 0, stream>>>(y, wt, lin_b, out);
    forward_kernel<<<NBATCH, 256, 0, stream>>>(out, corr);
    sub_kernel<<<(out_size / 4) / 256, 256, 0, stream>>>(out, corr);
}

// Round 3
// 1415.642 us; speedup vs baseline: 1.0117x; 1.0117x over previous
//
#include <hip/hip_runtime.h>
#include <hip/hip_bf16.h>
#include <hip/hip_fp16.h>
#include <type_traits>

// ---------------------------------------------------------------------------
// SeqdistModel (bonito CTC-CRF): conv(stride5)+tanh -> linear -> 5*tanh scores
// -> log-semiring forward (logZ) -> out = scores - logZ/T
// Shapes: x[32,1,4000], conv_w[320,1,19], conv_b[320], lin_w[320,5120],
//         lin_b[5120]; out [800,32,5120] fp32.
//
// R3: R2 design (bidirectional logZ: alpha fwd 0..479 || beta bwd 799..480 in
// one 64-block launch, fp16 score side-copy from GEMM epilogue, 512thr/8wave
// blocks) with the R2 sub_kernel grid bug fixed: out_size is in ELEMENTS, so
// the float4 sweep needs (out_size/4)/256 blocks (R2 used /16 -> 3/4 of the
// output never got corr subtracted; absmax 3.02 == corr).
// ---------------------------------------------------------------------------

typedef __attribute__((ext_vector_type(8))) short bf16x8;
typedef __attribute__((ext_vector_type(4))) float f32x4;

#define T_STEPS 800
#define NBATCH 32
#define FEAT 320
#define CNZ 5120
#define MROWS (T_STEPS * NBATCH)   // 25600
#define FSPLIT 480                 // forward steps; backward does 800-480=320
#define BSTEPS (T_STEPS - FSPLIT)

__device__ __forceinline__ float fast_tanh(float x) {
    float e = exp2f(x * 2.8853900817779268f);
    return 1.0f - 2.0f * __builtin_amdgcn_rcpf(e + 1.0f);
}

// ---- 1. conv (stride 5, SAME: pad 7/7) + tanh -> bf16 y[25600,320] ---------
__global__ __launch_bounds__(320) void conv_kernel(
    const float* __restrict__ x, const float* __restrict__ w,
    const float* __restrict__ b, __hip_bfloat16* __restrict__ y) {
    int m = blockIdx.x;            // m = t*32 + n
    int t = m >> 5, n = m & 31;
    int f = threadIdx.x;
    __shared__ float xs[19];
    int base = t * 5 - 7;
    if (f < 19) {
        int pos = base + f;
        xs[f] = (pos >= 0 && pos < 4000) ? x[n * 4000 + pos] : 0.0f;
    }
    __syncthreads();
    float acc = b[f];
#pragma unroll
    for (int k = 0; k < 19; ++k) acc = fmaf(xs[k], w[f * 19 + k], acc);
    y[(size_t)m * FEAT + f] = __float2bfloat16(fast_tanh(acc));
}

// ---- 2. transpose lin_w [320,5120] fp32 -> Wt [5120,320] bf16 --------------
__global__ __launch_bounds__(256) void transpose_w(
    const float* __restrict__ W, __hip_bfloat16* __restrict__ Wt) {
    __shared__ float tile[64][65];
    int nb = blockIdx.x * 64, kb = blockIdx.y * 64;
    int tx = threadIdx.x & 63, ty = threadIdx.x >> 6;   // 64 x 4
#pragma unroll
    for (int r = 0; r < 64; r += 4)
        tile[ty + r][tx] = W[(size_t)(kb + ty + r) * CNZ + nb + tx];
    __syncthreads();
#pragma unroll
    for (int r = 0; r < 64; r += 4) {
        int nn = ty + r;
        Wt[(size_t)(nb + nn) * FEAT + kb + tx] = __float2bfloat16(tile[tx][nn]);
    }
}

// ---- 3. GEMM: scores[m,n] = 5*tanh(sum_k A[m,k]*Wt[n,k] + bias[n]) ---------
#define GBM 128
#define GBN 128
#define GBK 64
#define LDK 72

__global__ __launch_bounds__(256) void gemm_kernel(
    const __hip_bfloat16* __restrict__ A,    // [25600,320] bf16
    const __hip_bfloat16* __restrict__ Bt,   // [5120,320]  bf16
    const float* __restrict__ bias,          // [5120]
    float* __restrict__ out,                 // [25600,5120] fp32
    __half* __restrict__ s16) {              // optional fp16 copy (may be null)
    __shared__ __align__(16) short As[GBM * LDK];
    __shared__ __align__(16) short Bs[GBN * LDK];
    const int K = FEAT;
    int bm0 = blockIdx.x * GBM;
    int bn0 = blockIdx.y * GBN;
    int tid = threadIdx.x;
    int wave = tid >> 6, lane = tid & 63;
    int wm = (wave >> 1) * 64, wn = (wave & 1) * 64;
    int col = lane & 15, quad = lane >> 4;

    f32x4 acc[4][4];
#pragma unroll
    for (int i = 0; i < 4; ++i)
#pragma unroll
        for (int j = 0; j < 4; ++j) acc[i][j] = (f32x4){0.f, 0.f, 0.f, 0.f};

    for (int k0 = 0; k0 < K; k0 += GBK) {
#pragma unroll
        for (int p = 0; p < 4; ++p) {
            int i = p * 256 + tid;
            int row = i >> 3, cg = i & 7;
            *(int4*)&As[row * LDK + cg * 8] =
                *(const int4*)&A[(size_t)(bm0 + row) * K + k0 + cg * 8];
            *(int4*)&Bs[row * LDK + cg * 8] =
                *(const int4*)&Bt[(size_t)(bn0 + row) * K + k0 + cg * 8];
        }
        __syncthreads();
#pragma unroll
        for (int kk = 0; kk < GBK; kk += 32) {
            bf16x8 af[4], bfr[4];
#pragma unroll
            for (int i = 0; i < 4; ++i)
                af[i] = *(bf16x8*)&As[(wm + i * 16 + col) * LDK + kk + quad * 8];
#pragma unroll
            for (int j = 0; j < 4; ++j)
                bfr[j] = *(bf16x8*)&Bs[(wn + j * 16 + col) * LDK + kk + quad * 8];
#pragma unroll
            for (int i = 0; i < 4; ++i)
#pragma unroll
                for (int j = 0; j < 4; ++j)
                    acc[i][j] = __builtin_amdgcn_mfma_f32_16x16x32_bf16(
                        af[i], bfr[j], acc[i][j], 0, 0, 0);
        }
        __syncthreads();
    }
#pragma unroll
    for (int j = 0; j < 4; ++j) {
        int n_g = bn0 + wn + j * 16 + col;
        float bj = bias[n_g];
#pragma unroll
        for (int i = 0; i < 4; ++i) {
            int m_base = bm0 + wm + i * 16 + quad * 4;
#pragma unroll
            for (int r = 0; r < 4; ++r) {
                size_t idx = (size_t)(m_base + r) * CNZ + n_g;
                float v = 5.0f * fast_tanh(acc[i][j][r] + bj);
                out[idx] = v;
                if (s16) s16[idx] = __float2half(v);
            }
        }
    }
}

// ---- 4. bidirectional logZ -------------------------------------------------
// alpha_{t+1}[c] = lse_z(Ms[t,c,z] + alpha_t[idx[c,z]]),
//   idx[c] = {c, q, q+256, q+512, q+768}, q=c>>2.
// beta_t[p]  = lse( Ms[t,p,0]+beta_{t+1}[p],
//                   Ms[t,4(p&255)+j,1+(p>>8)]+beta_{t+1}[4(p&255)+j], j=0..3 )
// logZ = lse_c(alpha_FSPLIT[c] + beta_FSPLIT[c]).  All in log2 domain.
// 64 blocks: n = bid&31, dir = bid>>5.  512 thr x 2 states (8 waves).

__device__ __forceinline__ float lse5_2(float s0, float s1, float s2, float s3,
                                        float s4, float a0, float a1, float a2,
                                        float a3, float a4) {
    const float L2E = 1.4426950408889634f;
    float x0 = fmaf(s0, L2E, a0);
    float x1 = fmaf(s1, L2E, a1);
    float x2 = fmaf(s2, L2E, a2);
    float x3 = fmaf(s3, L2E, a3);
    float x4 = fmaf(s4, L2E, a4);
    float mx = fmaxf(fmaxf(fmaxf(x0, x1), fmaxf(x2, x3)), x4);
    float sum = __builtin_amdgcn_exp2f(x0 - mx) + __builtin_amdgcn_exp2f(x1 - mx) +
                __builtin_amdgcn_exp2f(x2 - mx) + __builtin_amdgcn_exp2f(x3 - mx) +
                __builtin_amdgcn_exp2f(x4 - mx);
    return __builtin_amdgcn_logf(sum) + mx;   // log2(sum) + mx
}

__device__ __forceinline__ float cvh(ushort u) { __half h = *(__half*)&u; return __half2float(h); }
__device__ __forceinline__ float cvh(float f) { return f; }

template<bool FP16>
__global__ __launch_bounds__(512) void fb_kernel(
    const void* __restrict__ sc, float* __restrict__ alphaF,
    float* __restrict__ betaB) {
    __shared__ __align__(16) float A0[1024];
    __shared__ __align__(16) float A1[1024];
    const int tid = threadIdx.x;
    const int n = blockIdx.x & 31;
    const int dir = blockIdx.x >> 5;

    *(float2*)&A0[2 * tid] = make_float2(0.f, 0.f);
    __syncthreads();

    const size_t row = (size_t)NBATCH * CNZ;   // elements per time step

    if (dir == 0) {
        // ------------------------- forward -------------------------
        const int q = tid >> 1;                // shared predecessor quad
        const uint* fbu = (const uint*)((const __half*)sc + (size_t)n * CNZ) +
                          (size_t)tid * 5;     // fp16: 10 halves = 5 uints
        const float2* fbf = (const float2*)((const float*)sc + (size_t)n * CNZ +
                          (size_t)tid * 10);   // fp32: 10 floats = 5 float2

#define LDF(P, TT) do { int tc_ = (TT) < FSPLIT ? (TT) : (FSPLIT - 1);         \
    if constexpr (FP16) { const uint* pp_ = fbu + (size_t)tc_ * 81920;         \
        P[0] = pp_[0]; P[1] = pp_[1]; P[2] = pp_[2]; P[3] = pp_[3]; P[4] = pp_[4]; } \
    else { const float2* pp_ = fbf + (size_t)tc_ * 81920; float2* d_ = (float2*)P; \
        d_[0] = pp_[0]; d_[1] = pp_[1]; d_[2] = pp_[2]; d_[3] = pp_[3]; d_[4] = pp_[4]; } \
} while (0)

#define UNP(P, s) do { if constexpr (FP16) {                                   \
        float2 f0_ = __half22float2(*(__half2*)&P[0]);                         \
        float2 f1_ = __half22float2(*(__half2*)&P[1]);                         \
        float2 f2_ = __half22float2(*(__half2*)&P[2]);                         \
        float2 f3_ = __half22float2(*(__half2*)&P[3]);                         \
        float2 f4_ = __half22float2(*(__half2*)&P[4]);                         \
        s[0]=f0_.x; s[1]=f0_.y; s[2]=f1_.x; s[3]=f1_.y; s[4]=f2_.x;            \
        s[5]=f2_.y; s[6]=f3_.x; s[7]=f3_.y; s[8]=f4_.x; s[9]=f4_.y; }          \
    else { const float* f_ = (const float*)P;                                  \
        s[0]=f_[0]; s[1]=f_[1]; s[2]=f_[2]; s[3]=f_[3]; s[4]=f_[4];            \
        s[5]=f_[5]; s[6]=f_[6]; s[7]=f_[7]; s[8]=f_[8]; s[9]=f_[9]; }          \
} while (0)

#define FSTEP(P, TT, cur, nxt) do { float s_[10]; UNP(P, s_); LDF(P, TT);      \
    float aq0_ = (cur)[q], aq1_ = (cur)[q + 256];                              \
    float aq2_ = (cur)[q + 512], aq3_ = (cur)[q + 768];                        \
    float2 ao_ = *(const float2*)&(cur)[2 * tid];                              \
    float r0_ = lse5_2(s_[0], s_[1], s_[2], s_[3], s_[4], ao_.x, aq0_, aq1_, aq2_, aq3_); \
    float r1_ = lse5_2(s_[5], s_[6], s_[7], s_[8], s_[9], ao_.y, aq0_, aq1_, aq2_, aq3_); \
    *(float2*)&(nxt)[2 * tid] = make_float2(r0_, r1_);                         \
    __syncthreads();                                                           \
} while (0)

        uint P0[10], P1[10], P2[10], P3[10];
        LDF(P0, 0); LDF(P1, 1); LDF(P2, 2); LDF(P3, 3);
        for (int t = 0; t < FSPLIT; t += 4) {
            FSTEP(P0, t + 4, A0, A1);
            FSTEP(P1, t + 5, A1, A0);
            FSTEP(P2, t + 6, A0, A1);
            FSTEP(P3, t + 7, A1, A0);
        }
        // FSPLIT divisible by 4 -> final alpha2 in A0
        *(float2*)&alphaF[(size_t)n * 1024 + 2 * tid] = *(const float2*)&A0[2 * tid];
    } else {
        // ------------------------- backward ------------------------
        using ET = std::conditional_t<FP16, ushort, float>;
        const int p0 = 2 * tid;
        const int g = p0 & 255;
        const int hi = p0 >> 8;
        const size_t o_self = (size_t)10 * tid;          // Ms[p0,0]
        const size_t gb = (size_t)20 * g + 1 + hi;       // gather base
        const ET* bb = (const ET*)sc + (size_t)n * CNZ;
        const int sbase = (8 * tid) & 1023;              // 4*(p0&255)

#define LDB(E, KK) do { int kc_ = (KK) < BSTEPS ? (KK) : (BSTEPS - 1);         \
    const ET* pb_ = bb + (size_t)(T_STEPS - 1 - kc_) * row;                    \
    E[0] = pb_[o_self];      E[1] = pb_[gb];       E[2] = pb_[gb + 5];         \
    E[3] = pb_[gb + 10];     E[4] = pb_[gb + 15];  E[5] = pb_[o_self + 5];     \
    E[6] = pb_[gb + 20];     E[7] = pb_[gb + 25];  E[8] = pb_[gb + 30];        \
    E[9] = pb_[gb + 35];                                                       \
} while (0)

#define BSTEP(E, KK, cur, nxt) do { float s_[10];                              \
    s_[0]=cvh(E[0]); s_[1]=cvh(E[1]); s_[2]=cvh(E[2]); s_[3]=cvh(E[3]);        \
    s_[4]=cvh(E[4]); s_[5]=cvh(E[5]); s_[6]=cvh(E[6]); s_[7]=cvh(E[7]);        \
    s_[8]=cvh(E[8]); s_[9]=cvh(E[9]); LDB(E, KK);                              \
    float2 bs_ = *(const float2*)&(cur)[2 * tid];                              \
    float4 b0_ = *(const float4*)&(cur)[sbase];                                \
    float4 b1_ = *(const float4*)&(cur)[sbase + 4];                            \
    float r0_ = lse5_2(s_[0], s_[1], s_[2], s_[3], s_[4], bs_.x, b0_.x, b0_.y, b0_.z, b0_.w); \
    float r1_ = lse5_2(s_[5], s_[6], s_[7], s_[8], s_[9], bs_.y, b1_.x, b1_.y, b1_.z, b1_.w); \
    *(float2*)&(nxt)[2 * tid] = make_float2(r0_, r1_);                         \
    __syncthreads();                                                           \
} while (0)

        ET E0[10], E1[10], E2[10], E3[10];
        LDB(E0, 0); LDB(E1, 1); LDB(E2, 2); LDB(E3, 3);
        for (int k = 0; k < BSTEPS; k += 4) {
            BSTEP(E0, k + 4, A0, A1);
            BSTEP(E1, k + 5, A1, A0);
            BSTEP(E2, k + 6, A0, A1);
            BSTEP(E3, k + 7, A1, A0);
        }
        // BSTEPS divisible by 4 -> final beta2 in A0
        *(float2*)&betaB[(size_t)n * 1024 + 2 * tid] = *(const float2*)&A0[2 * tid];
    }
}

// ---- 4b. combine: corr[n] = lse_c(alpha2+beta2) * ln2 / T ------------------
__global__ __launch_bounds__(256) void combine_kernel(
    const float* __restrict__ aF, const float* __restrict__ bB,
    float* __restrict__ corr) {
    __shared__ float R[256];
    int n = blockIdx.x, tid = threadIdx.x;
    float4 a = *(const float4*)&aF[(size_t)n * 1024 + 4 * tid];
    float4 b = *(const float4*)&bB[(size_t)n * 1024 + 4 * tid];
    float x0 = a.x + b.x, x1 = a.y + b.y, x2 = a.z + b.z, x3 = a.w + b.w;
    float m = fmaxf(fmaxf(x0, x1), fmaxf(x2, x3));
    R[tid] = m;
    __syncthreads();
#pragma unroll
    for (int s = 128; s > 0; s >>= 1) {
        if (tid < s) R[tid] = fmaxf(R[tid], R[tid + s]);
        __syncthreads();
    }
    float mx = R[0];
    __syncthreads();
    float sm = exp2f(x0 - mx) + exp2f(x1 - mx) + exp2f(x2 - mx) + exp2f(x3 - mx);
    R[tid] = sm;
    __syncthreads();
#pragma unroll
    for (int s = 128; s > 0; s >>= 1) {
        if (tid < s) R[tid] += R[tid + s];
        __syncthreads();
    }
    if (tid == 0)
        corr[n] = (log2f(R[0]) + mx) * 0.6931471805599453f * (1.0f / (float)T_STEPS);
}

// ---- 5. out -= corr[n]  (float4; out_size is in ELEMENTS -> /4 per thread) -
__global__ __launch_bounds__(256) void sub_kernel(
    float* __restrict__ out, const float* __restrict__ corr) {
    size_t i4 = (size_t)blockIdx.x * blockDim.x + threadIdx.x;
    float cc = corr[(i4 / (CNZ / 4)) & (NBATCH - 1)];
    float4* o4 = (float4*)out;
    float4 v = o4[i4];
    v.x -= cc; v.y -= cc; v.z -= cc; v.w -= cc;
    o4[i4] = v;
}

extern "C" void kernel_launch(void* const* d_in, const int* in_sizes, int n_in,
                              void* d_out, int out_size, void* d_ws, size_t ws_size,
                              hipStream_t stream) {
    const float* x      = (const float*)d_in[0];
    const float* conv_w = (const float*)d_in[1];
    const float* conv_b = (const float*)d_in[2];
    const float* lin_w  = (const float*)d_in[3];
    const float* lin_b  = (const float*)d_in[4];
    float* out = (float*)d_out;

    // workspace layout (bytes)
    const size_t Y_OFF    = 0;                 // 16,384,000
    const size_t WT_OFF   = 16384000;          //  3,276,800
    const size_t CORR_OFF = 19660800;          //        256
    const size_t AF_OFF   = 19661056;          //    131,072
    const size_t BB_OFF   = 19792128;          //    131,072
    const size_t S16_OFF  = 19923200;          // 262,144,000
    const size_t NEED16   = S16_OFF + (size_t)MROWS * CNZ * 2;

    char* ws = (char*)d_ws;
    __hip_bfloat16* y  = (__hip_bfloat16*)(ws + Y_OFF);
    __hip_bfloat16* wt = (__hip_bfloat16*)(ws + WT_OFF);
    float* corr = (float*)(ws + CORR_OFF);
    float* aF   = (float*)(ws + AF_OFF);
    float* bB   = (float*)(ws + BB_OFF);
    bool fp16_path = ws_size >= NEED16;
    __half* s16 = fp16_path ? (__half*)(ws + S16_OFF) : nullptr;

    conv_kernel<<<MROWS, 320, 0, stream>>>(x, conv_w, conv_b, y);
    transpose_w<<<dim3(CNZ / 64, FEAT / 64), 256, 0, stream>>>(lin_w, wt);
    gemm_kernel<<<dim3(MROWS / GBM, CNZ / GBN), 256, 0, stream>>>(y, wt, lin_b, out, s16);
    if (fp16_path)
        fb_kernel<true><<<64, 512, 0, stream>>>(s16, aF, bB);
    else
        fb_kernel<false><<<64, 512, 0, stream>>>(out, aF, bB);
    combine_kernel<<<NBATCH, 256, 0, stream>>>(aF, bB, corr);
    sub_kernel<<<(out_size / 4) / 256, 256, 0, stream>>>(out, corr);
}

// Round 4
// 1314.388 us; speedup vs baseline: 1.0896x; 1.0770x over previous
//
#include <hip/hip_runtime.h>
#include <hip/hip_bf16.h>
#include <hip/hip_fp16.h>

// ---------------------------------------------------------------------------
// SeqdistModel (bonito CTC-CRF): conv(stride5)+tanh -> linear -> 5*tanh scores
// -> log-semiring forward (logZ) -> out = scores - logZ/T
// Shapes: x[32,1,4000], conv_w[320,1,19], conv_b[320], lin_w[320,5120],
//         lin_b[5120]; out [800,32,5120] fp32.
//
// R4: backward direction reads a TRANSPOSED fp16 score copy sT[m][z][c]
// (written by the GEMM epilogue) so its per-step gather is one dwordx4 + one
// dword instead of 10 scattered ushort loads. Split rebalanced 400/400.
// Tier A (ws >= 544MB): GEMM writes only s16(natural)+sT; sub materializes
// out = half(s)-corr. Tier B (ws >= 282MB, proven): fp32 out + sT.
// ---------------------------------------------------------------------------

typedef __attribute__((ext_vector_type(8))) short bf16x8;
typedef __attribute__((ext_vector_type(4))) float f32x4;
typedef unsigned int uint4u __attribute__((ext_vector_type(4), aligned(4)));

#define T_STEPS 800
#define NBATCH 32
#define FEAT 320
#define CNZ 5120
#define MROWS (T_STEPS * NBATCH)   // 25600
#define FSPLIT 400                 // forward steps (divisible by 4)
#define BSTEPS (T_STEPS - FSPLIT)  // 400 backward steps
#define ROWB 327680                // bytes per time step in fp16 copies (32*5120*2)

__device__ __forceinline__ float fast_tanh(float x) {
    float e = exp2f(x * 2.8853900817779268f);
    return 1.0f - 2.0f * __builtin_amdgcn_rcpf(e + 1.0f);
}

__device__ __forceinline__ float2 h2f(uint u) {
    __half2 h = *(__half2*)&u;
    return __half22float2(h);
}

// ---- 1. conv (stride 5, SAME: pad 7/7) + tanh -> bf16 y[25600,320] ---------
__global__ __launch_bounds__(320) void conv_kernel(
    const float* __restrict__ x, const float* __restrict__ w,
    const float* __restrict__ b, __hip_bfloat16* __restrict__ y) {
    int m = blockIdx.x;            // m = t*32 + n
    int t = m >> 5, n = m & 31;
    int f = threadIdx.x;
    __shared__ float xs[19];
    int base = t * 5 - 7;
    if (f < 19) {
        int pos = base + f;
        xs[f] = (pos >= 0 && pos < 4000) ? x[n * 4000 + pos] : 0.0f;
    }
    __syncthreads();
    float acc = b[f];
#pragma unroll
    for (int k = 0; k < 19; ++k) acc = fmaf(xs[k], w[f * 19 + k], acc);
    y[(size_t)m * FEAT + f] = __float2bfloat16(fast_tanh(acc));
}

// ---- 2. transpose lin_w [320,5120] fp32 -> Wt [5120,320] bf16 --------------
__global__ __launch_bounds__(256) void transpose_w(
    const float* __restrict__ W, __hip_bfloat16* __restrict__ Wt) {
    __shared__ float tile[64][65];
    int nb = blockIdx.x * 64, kb = blockIdx.y * 64;
    int tx = threadIdx.x & 63, ty = threadIdx.x >> 6;   // 64 x 4
#pragma unroll
    for (int r = 0; r < 64; r += 4)
        tile[ty + r][tx] = W[(size_t)(kb + ty + r) * CNZ + nb + tx];
    __syncthreads();
#pragma unroll
    for (int r = 0; r < 64; r += 4) {
        int nn = ty + r;
        Wt[(size_t)(nb + nn) * FEAT + kb + tx] = __float2bfloat16(tile[tx][nn]);
    }
}

// ---- 3. GEMM: scores[m,n] = 5*tanh(sum_k A[m,k]*Wt[n,k] + bias[n]) ---------
#define GBM 128
#define GBN 128
#define GBK 64
#define LDK 72

__global__ __launch_bounds__(256) void gemm_kernel(
    const __hip_bfloat16* __restrict__ A,    // [25600,320] bf16
    const __hip_bfloat16* __restrict__ Bt,   // [5120,320]  bf16
    const float* __restrict__ bias,          // [5120]
    float* __restrict__ out,                 // [25600,5120] fp32 (may be skipped)
    __half* __restrict__ s16n,               // natural fp16 copy (or null)
    __half* __restrict__ s16t,               // transposed [m][z][c] copy (or null)
    int write_out) {
    __shared__ __align__(16) short As[GBM * LDK];
    __shared__ __align__(16) short Bs[GBN * LDK];
    const int K = FEAT;
    int bm0 = blockIdx.x * GBM;
    int bn0 = blockIdx.y * GBN;
    int tid = threadIdx.x;
    int wave = tid >> 6, lane = tid & 63;
    int wm = (wave >> 1) * 64, wn = (wave & 1) * 64;
    int col = lane & 15, quad = lane >> 4;

    f32x4 acc[4][4];
#pragma unroll
    for (int i = 0; i < 4; ++i)
#pragma unroll
        for (int j = 0; j < 4; ++j) acc[i][j] = (f32x4){0.f, 0.f, 0.f, 0.f};

    for (int k0 = 0; k0 < K; k0 += GBK) {
#pragma unroll
        for (int p = 0; p < 4; ++p) {
            int i = p * 256 + tid;
            int row = i >> 3, cg = i & 7;
            *(int4*)&As[row * LDK + cg * 8] =
                *(const int4*)&A[(size_t)(bm0 + row) * K + k0 + cg * 8];
            *(int4*)&Bs[row * LDK + cg * 8] =
                *(const int4*)&Bt[(size_t)(bn0 + row) * K + k0 + cg * 8];
        }
        __syncthreads();
#pragma unroll
        for (int kk = 0; kk < GBK; kk += 32) {
            bf16x8 af[4], bfr[4];
#pragma unroll
            for (int i = 0; i < 4; ++i)
                af[i] = *(bf16x8*)&As[(wm + i * 16 + col) * LDK + kk + quad * 8];
#pragma unroll
            for (int j = 0; j < 4; ++j)
                bfr[j] = *(bf16x8*)&Bs[(wn + j * 16 + col) * LDK + kk + quad * 8];
#pragma unroll
            for (int i = 0; i < 4; ++i)
#pragma unroll
                for (int j = 0; j < 4; ++j)
                    acc[i][j] = __builtin_amdgcn_mfma_f32_16x16x32_bf16(
                        af[i], bfr[j], acc[i][j], 0, 0, 0);
        }
        __syncthreads();
    }
#pragma unroll
    for (int j = 0; j < 4; ++j) {
        int n_g = bn0 + wn + j * 16 + col;
        float bj = bias[n_g];
        uint c = (uint)n_g / 5u;            // compiler magic-mul
        uint z = (uint)n_g - 5u * c;
        size_t t_off = (size_t)z * 1024 + c;
#pragma unroll
        for (int i = 0; i < 4; ++i) {
            int m_base = bm0 + wm + i * 16 + quad * 4;
#pragma unroll
            for (int r = 0; r < 4; ++r) {
                int m = m_base + r;
                size_t idx = (size_t)m * CNZ + n_g;
                float v = 5.0f * fast_tanh(acc[i][j][r] + bj);
                if (write_out) out[idx] = v;
                __half hv = __float2half(v);
                if (s16n) s16n[idx] = hv;
                if (s16t) s16t[(size_t)m * CNZ + t_off] = hv;
            }
        }
    }
}

// ---- 4. bidirectional logZ -------------------------------------------------
// alpha_{t+1}[c] = lse_z(Ms[t,c,z] + alpha_t[idx[c,z]]),
//   idx[c] = {c, q, q+256, q+512, q+768}, q=c>>2.
// beta_t[p]  = lse( Ms[t,p,0]+beta_{t+1}[p],
//                   Ms[t,4(p&255)+j,1+(p>>8)]+beta_{t+1}[4(p&255)+j], j=0..3 )
// logZ = lse_c(alpha_FSPLIT[c] + beta_FSPLIT[c]).  All in log2 domain.
// 64 blocks: n = bid&31, dir = bid>>5.  512 thr x 2 states (8 waves).
// MODE 2: fwd reads s16 natural, bwd reads sT.  MODE 1: fwd fp32 out, bwd sT.
// MODE 0: both from fp32 out (fallback).

__device__ __forceinline__ float lse5_2(float s0, float s1, float s2, float s3,
                                        float s4, float a0, float a1, float a2,
                                        float a3, float a4) {
    const float L2E = 1.4426950408889634f;
    float x0 = fmaf(s0, L2E, a0);
    float x1 = fmaf(s1, L2E, a1);
    float x2 = fmaf(s2, L2E, a2);
    float x3 = fmaf(s3, L2E, a3);
    float x4 = fmaf(s4, L2E, a4);
    float mx = fmaxf(fmaxf(fmaxf(x0, x1), fmaxf(x2, x3)), x4);
    float sum = __builtin_amdgcn_exp2f(x0 - mx) + __builtin_amdgcn_exp2f(x1 - mx) +
                __builtin_amdgcn_exp2f(x2 - mx) + __builtin_amdgcn_exp2f(x3 - mx) +
                __builtin_amdgcn_exp2f(x4 - mx);
    return __builtin_amdgcn_logf(sum) + mx;   // log2(sum) + mx
}

template<int MODE>
__global__ __launch_bounds__(512) void fb_kernel(
    const void* __restrict__ nat, const void* __restrict__ tr,
    float* __restrict__ alphaF, float* __restrict__ betaB) {
    __shared__ __align__(16) float A0[1024];
    __shared__ __align__(16) float A1[1024];
    const int tid = threadIdx.x;
    const int n = blockIdx.x & 31;
    const int dir = blockIdx.x >> 5;

    *(float2*)&A0[2 * tid] = make_float2(0.f, 0.f);
    __syncthreads();

    if (dir == 0) {
        // ------------------------- forward -------------------------
        const int q = tid >> 1;                // shared predecessor quad

        if constexpr (MODE == 2) {
            const char* fbn = (const char*)nat +
                              ((size_t)n * CNZ + (size_t)tid * 10) * 2;

#define LDF2(V, S, TT) do { int tc_ = (TT) < FSPLIT ? (TT) : (FSPLIT - 1);     \
    const char* p_ = fbn + (size_t)tc_ * ROWB;                                 \
    V = *(const uint4u*)p_; S = *(const uint*)(p_ + 16);                       \
} while (0)

#define FSTEP2(V, S, TT, cur, nxt) do {                                        \
    float2 f0_ = h2f(V.x), f1_ = h2f(V.y), f2_ = h2f(V.z), f3_ = h2f(V.w);     \
    float2 f4_ = h2f(S);                                                       \
    LDF2(V, S, TT);                                                            \
    float aq0_ = (cur)[q], aq1_ = (cur)[q + 256];                              \
    float aq2_ = (cur)[q + 512], aq3_ = (cur)[q + 768];                        \
    float2 ao_ = *(const float2*)&(cur)[2 * tid];                              \
    float r0_ = lse5_2(f0_.x, f0_.y, f1_.x, f1_.y, f2_.x, ao_.x, aq0_, aq1_, aq2_, aq3_); \
    float r1_ = lse5_2(f2_.y, f3_.x, f3_.y, f4_.x, f4_.y, ao_.y, aq0_, aq1_, aq2_, aq3_); \
    *(float2*)&(nxt)[2 * tid] = make_float2(r0_, r1_);                         \
    __syncthreads();                                                           \
} while (0)

            uint4u P0v, P1v, P2v, P3v;
            uint P0s, P1s, P2s, P3s;
            LDF2(P0v, P0s, 0); LDF2(P1v, P1s, 1);
            LDF2(P2v, P2s, 2); LDF2(P3v, P3s, 3);
            for (int t = 0; t < FSPLIT; t += 4) {
                FSTEP2(P0v, P0s, t + 4, A0, A1);
                FSTEP2(P1v, P1s, t + 5, A1, A0);
                FSTEP2(P2v, P2s, t + 6, A0, A1);
                FSTEP2(P3v, P3s, t + 7, A1, A0);
            }
        } else {
            const float2* fbf = (const float2*)((const float*)nat +
                                (size_t)n * CNZ + (size_t)tid * 10);

#define LDF1(Q, TT) do { int tc_ = (TT) < FSPLIT ? (TT) : (FSPLIT - 1);        \
    const float2* p_ = fbf + (size_t)tc_ * 81920;                              \
    Q[0] = p_[0]; Q[1] = p_[1]; Q[2] = p_[2]; Q[3] = p_[3]; Q[4] = p_[4];      \
} while (0)

#define FSTEP1(Q, TT, cur, nxt) do {                                           \
    float s0_ = Q[0].x, s1_ = Q[0].y, s2_ = Q[1].x, s3_ = Q[1].y, s4_ = Q[2].x;\
    float u0_ = Q[2].y, u1_ = Q[3].x, u2_ = Q[3].y, u3_ = Q[4].x, u4_ = Q[4].y;\
    LDF1(Q, TT);                                                               \
    float aq0_ = (cur)[q], aq1_ = (cur)[q + 256];                              \
    float aq2_ = (cur)[q + 512], aq3_ = (cur)[q + 768];                        \
    float2 ao_ = *(const float2*)&(cur)[2 * tid];                              \
    float r0_ = lse5_2(s0_, s1_, s2_, s3_, s4_, ao_.x, aq0_, aq1_, aq2_, aq3_);\
    float r1_ = lse5_2(u0_, u1_, u2_, u3_, u4_, ao_.y, aq0_, aq1_, aq2_, aq3_);\
    *(float2*)&(nxt)[2 * tid] = make_float2(r0_, r1_);                         \
    __syncthreads();                                                           \
} while (0)

            float2 Q0[5], Q1[5], Q2[5], Q3[5];
            LDF1(Q0, 0); LDF1(Q1, 1); LDF1(Q2, 2); LDF1(Q3, 3);
            for (int t = 0; t < FSPLIT; t += 4) {
                FSTEP1(Q0, t + 4, A0, A1);
                FSTEP1(Q1, t + 5, A1, A0);
                FSTEP1(Q2, t + 6, A0, A1);
                FSTEP1(Q3, t + 7, A1, A0);
            }
        }
        // FSPLIT divisible by 4 -> final alpha2 in A0
        *(float2*)&alphaF[(size_t)n * 1024 + 2 * tid] = *(const float2*)&A0[2 * tid];
    } else {
        // ------------------------- backward ------------------------
        const int p0 = 2 * tid;
        const int g = p0 & 255;
        const int hi = p0 >> 8;
        const int sbase = (8 * tid) & 1023;              // 4*(p0&255)

        if constexpr (MODE >= 1) {
            // sT[m][z][c]: gather (z=1+hi, c=4g..4g+7) = one 16B load;
            // self (z=0, c=p0,p0+1) = one 4B load.
            const char* btg = (const char*)tr +
                ((size_t)n * CNZ + (size_t)(1 + hi) * 1024 + (size_t)(4 * g)) * 2;
            const char* bts = (const char*)tr +
                ((size_t)n * CNZ + (size_t)p0) * 2;

#define LDB2(V, S, KK) do { int kc_ = (KK) < BSTEPS ? (KK) : (BSTEPS - 1);     \
    size_t o_ = (size_t)(T_STEPS - 1 - kc_) * ROWB;                            \
    V = *(const uint4u*)(btg + o_); S = *(const uint*)(bts + o_);              \
} while (0)

#define BSTEP2(V, S, KK, cur, nxt) do {                                        \
    float2 g0_ = h2f(V.x), g1_ = h2f(V.y), g2_ = h2f(V.z), g3_ = h2f(V.w);     \
    float2 sf_ = h2f(S);                                                       \
    LDB2(V, S, KK);                                                            \
    float2 bs_ = *(const float2*)&(cur)[2 * tid];                              \
    float4 b0_ = *(const float4*)&(cur)[sbase];                                \
    float4 b1_ = *(const float4*)&(cur)[sbase + 4];                            \
    float r0_ = lse5_2(sf_.x, g0_.x, g0_.y, g1_.x, g1_.y, bs_.x, b0_.x, b0_.y, b0_.z, b0_.w); \
    float r1_ = lse5_2(sf_.y, g2_.x, g2_.y, g3_.x, g3_.y, bs_.y, b1_.x, b1_.y, b1_.z, b1_.w); \
    *(float2*)&(nxt)[2 * tid] = make_float2(r0_, r1_);                         \
    __syncthreads();                                                           \
} while (0)

            uint4u E0v, E1v, E2v, E3v;
            uint E0s, E1s, E2s, E3s;
            LDB2(E0v, E0s, 0); LDB2(E1v, E1s, 1);
            LDB2(E2v, E2s, 2); LDB2(E3v, E3s, 3);
            for (int k = 0; k < BSTEPS; k += 4) {
                BSTEP2(E0v, E0s, k + 4, A0, A1);
                BSTEP2(E1v, E1s, k + 5, A1, A0);
                BSTEP2(E2v, E2s, k + 6, A0, A1);
                BSTEP2(E3v, E3s, k + 7, A1, A0);
            }
        } else {
            // fallback: scattered fp32 gather from natural layout
            const size_t o_self = (size_t)10 * tid;
            const size_t gb = (size_t)20 * g + 1 + hi;
            const float* bb = (const float*)nat + (size_t)n * CNZ;
            const size_t row = (size_t)NBATCH * CNZ;

#define LDB1(E, KK) do { int kc_ = (KK) < BSTEPS ? (KK) : (BSTEPS - 1);        \
    const float* pb_ = bb + (size_t)(T_STEPS - 1 - kc_) * row;                 \
    E[0] = pb_[o_self];      E[1] = pb_[gb];       E[2] = pb_[gb + 5];         \
    E[3] = pb_[gb + 10];     E[4] = pb_[gb + 15];  E[5] = pb_[o_self + 5];     \
    E[6] = pb_[gb + 20];     E[7] = pb_[gb + 25];  E[8] = pb_[gb + 30];        \
    E[9] = pb_[gb + 35];                                                       \
} while (0)

#define BSTEP1(E, KK, cur, nxt) do {                                           \
    float s0_=E[0], s1_=E[1], s2_=E[2], s3_=E[3], s4_=E[4];                    \
    float u0_=E[5], u1_=E[6], u2_=E[7], u3_=E[8], u4_=E[9];                    \
    LDB1(E, KK);                                                               \
    float2 bs_ = *(const float2*)&(cur)[2 * tid];                              \
    float4 b0_ = *(const float4*)&(cur)[sbase];                                \
    float4 b1_ = *(const float4*)&(cur)[sbase + 4];                            \
    float r0_ = lse5_2(s0_, s1_, s2_, s3_, s4_, bs_.x, b0_.x, b0_.y, b0_.z, b0_.w); \
    float r1_ = lse5_2(u0_, u1_, u2_, u3_, u4_, bs_.y, b1_.x, b1_.y, b1_.z, b1_.w); \
    *(float2*)&(nxt)[2 * tid] = make_float2(r0_, r1_);                         \
    __syncthreads();                                                           \
} while (0)

            float E0[10], E1[10], E2[10], E3[10];
            LDB1(E0, 0); LDB1(E1, 1); LDB1(E2, 2); LDB1(E3, 3);
            for (int k = 0; k < BSTEPS; k += 4) {
                BSTEP1(E0, k + 4, A0, A1);
                BSTEP1(E1, k + 5, A1, A0);
                BSTEP1(E2, k + 6, A0, A1);
                BSTEP1(E3, k + 7, A1, A0);
            }
        }
        // BSTEPS divisible by 4 -> final beta2 in A0
        *(float2*)&betaB[(size_t)n * 1024 + 2 * tid] = *(const float2*)&A0[2 * tid];
    }
}

// ---- 4b. combine: corr[n] = lse_c(alpha2+beta2) * ln2 / T ------------------
__global__ __launch_bounds__(256) void combine_kernel(
    const float* __restrict__ aF, const float* __restrict__ bB,
    float* __restrict__ corr) {
    __shared__ float R[256];
    int n = blockIdx.x, tid = threadIdx.x;
    float4 a = *(const float4*)&aF[(size_t)n * 1024 + 4 * tid];
    float4 b = *(const float4*)&bB[(size_t)n * 1024 + 4 * tid];
    float x0 = a.x + b.x, x1 = a.y + b.y, x2 = a.z + b.z, x3 = a.w + b.w;
    float m = fmaxf(fmaxf(x0, x1), fmaxf(x2, x3));
    R[tid] = m;
    __syncthreads();
#pragma unroll
    for (int s = 128; s > 0; s >>= 1) {
        if (tid < s) R[tid] = fmaxf(R[tid], R[tid + s]);
        __syncthreads();
    }
    float mx = R[0];
    __syncthreads();
    float sm = exp2f(x0 - mx) + exp2f(x1 - mx) + exp2f(x2 - mx) + exp2f(x3 - mx);
    R[tid] = sm;
    __syncthreads();
#pragma unroll
    for (int s = 128; s > 0; s >>= 1) {
        if (tid < s) R[tid] += R[tid + s];
        __syncthreads();
    }
    if (tid == 0)
        corr[n] = (log2f(R[0]) + mx) * 0.6931471805599453f * (1.0f / (float)T_STEPS);
}

// ---- 5a. out -= corr[n] in place (float4; out_size in ELEMENTS) ------------
__global__ __launch_bounds__(256) void sub_kernel(
    float* __restrict__ out, const float* __restrict__ corr) {
    size_t i4 = (size_t)blockIdx.x * blockDim.x + threadIdx.x;
    float cc = corr[(i4 / (CNZ / 4)) & (NBATCH - 1)];
    float4* o4 = (float4*)out;
    float4 v = o4[i4];
    v.x -= cc; v.y -= cc; v.z -= cc; v.w -= cc;
    o4[i4] = v;
}

// ---- 5b. out = half(s16) - corr[n]  (8 elems/thread) -----------------------
__global__ __launch_bounds__(256) void sub_mat_kernel(
    const __half* __restrict__ s16, const float* __restrict__ corr,
    float* __restrict__ out) {
    size_t i = (size_t)blockIdx.x * blockDim.x + threadIdx.x;   // 8-elem groups
    float cc = corr[(i / (CNZ / 8)) & (NBATCH - 1)];
    uint4 h = ((const uint4*)s16)[i];
    float2 f0 = h2f(h.x), f1 = h2f(h.y), f2 = h2f(h.z), f3 = h2f(h.w);
    float4 o0 = make_float4(f0.x - cc, f0.y - cc, f1.x - cc, f1.y - cc);
    float4 o1 = make_float4(f2.x - cc, f2.y - cc, f3.x - cc, f3.y - cc);
    ((float4*)out)[2 * i] = o0;
    ((float4*)out)[2 * i + 1] = o1;
}

extern "C" void kernel_launch(void* const* d_in, const int* in_sizes, int n_in,
                              void* d_out, int out_size, void* d_ws, size_t ws_size,
                              hipStream_t stream) {
    const float* x      = (const float*)d_in[0];
    const float* conv_w = (const float*)d_in[1];
    const float* conv_b = (const float*)d_in[2];
    const float* lin_w  = (const float*)d_in[3];
    const float* lin_b  = (const float*)d_in[4];
    float* out = (float*)d_out;

    // workspace layout (bytes)
    const size_t Y_OFF    = 0;                 // 16,384,000
    const size_t WT_OFF   = 16384000;          //  3,276,800
    const size_t CORR_OFF = 19660800;          //        256
    const size_t AF_OFF   = 19661056;          //    131,072
    const size_t BB_OFF   = 19792128;          //    131,072
    const size_t P0_OFF   = 19923200;          // fp16 copies start here
    const size_t SC_BYTES = (size_t)MROWS * CNZ * 2;   // 262,144,000 each
    const size_t NEED_A   = P0_OFF + 2 * SC_BYTES;     // 544,211,200
    const size_t NEED_B   = P0_OFF + SC_BYTES;         // 282,067,200 (proven fits)

    char* ws = (char*)d_ws;
    __hip_bfloat16* y  = (__hip_bfloat16*)(ws + Y_OFF);
    __hip_bfloat16* wt = (__hip_bfloat16*)(ws + WT_OFF);
    float* corr = (float*)(ws + CORR_OFF);
    float* aF   = (float*)(ws + AF_OFF);
    float* bB   = (float*)(ws + BB_OFF);

    __half* s16n = nullptr;
    __half* s16t = nullptr;
    int mode = 0;
    if (ws_size >= NEED_A) {
        s16n = (__half*)(ws + P0_OFF);
        s16t = (__half*)(ws + P0_OFF + SC_BYTES);
        mode = 2;
    } else if (ws_size >= NEED_B) {
        s16t = (__half*)(ws + P0_OFF);
        mode = 1;
    }

    conv_kernel<<<MROWS, 320, 0, stream>>>(x, conv_w, conv_b, y);
    transpose_w<<<dim3(CNZ / 64, FEAT / 64), 256, 0, stream>>>(lin_w, wt);
    gemm_kernel<<<dim3(MROWS / GBM, CNZ / GBN), 256, 0, stream>>>(
        y, wt, lin_b, out, s16n, s16t, mode != 2 ? 1 : 0);

    if (mode == 2)
        fb_kernel<2><<<64, 512, 0, stream>>>(s16n, s16t, aF, bB);
    else if (mode == 1)
        fb_kernel<1><<<64, 512, 0, stream>>>(out, s16t, aF, bB);
    else
        fb_kernel<0><<<64, 512, 0, stream>>>(out, nullptr, aF, bB);

    combine_kernel<<<NBATCH, 256, 0, stream>>>(aF, bB, corr);

    if (mode == 2)
        sub_mat_kernel<<<(out_size / 8) / 256, 256, 0, stream>>>(s16n, corr, out);
    else
        sub_kernel<<<(out_size / 4) / 256, 256, 0, stream>>>(out, corr);
}